// Round 6
// baseline (813.629 us; speedup 1.0000x reference)
//
#include <hip/hip_runtime.h>
#include <math.h>

#define NG 6
#define KD 40
#define CB 1024
#define NB 32
#define TP 2000
#define ROWS (NB * TP)      // 64000 rows per group
#define BLK 256
#define NBLK (ROWS / BLK)   // 250 blocks per group
#define ZSTRIDE_N 480000    // 240*2000 floats per batch element
#define ZSTRIDE_G 80000     // 40*2000 floats per group

// ---- prep: transpose embeddings (g,k,c) -> et[g][c][k] contiguous, plus fast ||e||^2
__global__ void prep_kernel(const float* __restrict__ emb,
                            float* __restrict__ et, float* __restrict__ e2) {
  int c = blockIdx.x * blockDim.x + threadIdx.x;
  int g = blockIdx.y;
  if (c >= CB) return;
  const float* eg = emb + (size_t)g * KD * CB;
  float* o = et + ((size_t)g * CB + c) * KD;
  float s = 0.f;
#pragma unroll
  for (int k = 0; k < KD; ++k) {
    float v = eg[k * CB + c];
    o[k] = v;
    s = fmaf(v, v, s);
  }
  e2[g * CB + c] = s;
}

// numpy-fp32-exact distance model (ref=np, all fp32):
//   dot: np.einsum generic SOP -> serial ascending-k, UNFUSED mul/add
//   ee : np.sum(emb**2, axis=1) strided reduce -> serial ascending-k, UNFUSED,
//        over pre-rounded squares
//   dist = fl(fl(x2 - fl(2*dot)) + ee)
__device__ __forceinline__ float np_dist(const float* __restrict__ x,
                                         const float* __restrict__ ec,
                                         float x2np) {
  float dot = 0.f, ee = 0.f;
#pragma unroll
  for (int k = 0; k < KD; ++k) {
    float ev = ec[k];
    dot = __fadd_rn(dot, __fmul_rn(x[k], ev));
    ee = __fadd_rn(ee, __fmul_rn(ev, ev));
  }
  return __fadd_rn(__fsub_rn(x2np, __fadd_rn(dot, dot)), ee);
}

// ---- main: one thread per (g, n, t) row
__global__ __launch_bounds__(BLK) void vq_kernel(
    const float* __restrict__ z, const float* __restrict__ et,
    const float* __restrict__ e2, float* __restrict__ out,
    float* __restrict__ partials) {
  const int g = blockIdx.y;
  const int rid = blockIdx.x * BLK + threadIdx.x;  // 0..63999
  const int n = rid / TP;
  const int t = rid - n * TP;

  const float* zp = z + (size_t)n * ZSTRIDE_N + (size_t)g * ZSTRIDE_G + t;
  float x[KD];
#pragma unroll
  for (int k = 0; k < KD; ++k) x[k] = zp[k * TP];
  float x2 = 0.f;
#pragma unroll
  for (int k = 0; k < KD; ++k) x2 = fmaf(x[k], x[k], x2);

  const float* etg = et + (size_t)g * CB * KD;  // wave-uniform base
  const float* e2g = e2 + g * CB;

  // pass 1: fast fp32 FMA scan tracking top-3 candidates (ranking only)
  float d1 = INFINITY, d2 = INFINITY, d3 = INFINITY;
  int i1 = 0, i2 = 0, i3 = 0;
  for (int c = 0; c < CB; ++c) {
    const float* ec = etg + c * KD;  // wave-uniform address
    float s0 = 0.f, s1 = 0.f, s2 = 0.f, s3 = 0.f;
#pragma unroll
    for (int k = 0; k < KD; k += 4) {
      s0 = fmaf(x[k + 0], ec[k + 0], s0);
      s1 = fmaf(x[k + 1], ec[k + 1], s1);
      s2 = fmaf(x[k + 2], ec[k + 2], s2);
      s3 = fmaf(x[k + 3], ec[k + 3], s3);
    }
    float dot = (s0 + s1) + (s2 + s3);
    float dist = (x2 - 2.0f * dot) + e2g[c];
    bool u1 = dist < d1;
    bool u2 = dist < d2;
    bool u3 = dist < d3;
    d3 = u2 ? d2 : (u3 ? dist : d3);
    i3 = u2 ? i2 : (u3 ? c : i3);
    d2 = u1 ? d1 : (u2 ? dist : d2);
    i2 = u1 ? i1 : (u2 ? c : i2);
    d1 = u1 ? dist : d1;
    i1 = u1 ? c : i1;
  }

  // pass 2: numpy-fp32-exact re-score of the three candidates.
  // x2np: np.sum(x**2, -1) pairwise for n=40: 8 accumulators over pre-rounded
  // squares, combined ((r0+r1)+(r2+r3))+((r4+r5)+(r6+r7)).
  float r[8];
#pragma unroll
  for (int j = 0; j < 8; ++j) r[j] = __fmul_rn(x[j], x[j]);
#pragma unroll
  for (int i = 8; i < KD; i += 8)
#pragma unroll
    for (int j = 0; j < 8; ++j)
      r[j] = __fadd_rn(r[j], __fmul_rn(x[i + j], x[i + j]));
  float x2np = __fadd_rn(__fadd_rn(__fadd_rn(r[0], r[1]), __fadd_rn(r[2], r[3])),
                         __fadd_rn(__fadd_rn(r[4], r[5]), __fadd_rn(r[6], r[7])));

  // evaluate candidates in ascending index order, strict < = np first-min
  int ca = i1, cb = i2, cc = i3, tmp;
  if (ca > cb) { tmp = ca; ca = cb; cb = tmp; }
  if (cb > cc) { tmp = cb; cb = cc; cc = tmp; }
  if (ca > cb) { tmp = ca; ca = cb; cb = tmp; }

  float da = np_dist(x, etg + ca * KD, x2np);
  float db = np_dist(x, etg + cb * KD, x2np);
  float dc = np_dist(x, etg + cc * KD, x2np);
  int bi = ca;
  float bd = da;
  if (db < bd) { bi = cb; bd = db; }
  if (dc < bd) { bi = cc; bd = dc; }

  // outputs: STE value fl(x + fl(q - x)) in fp32; commitment partial (q-x)^2
  const float* ew = etg + bi * KD;
  float* op = out + (size_t)n * ZSTRIDE_N + (size_t)g * ZSTRIDE_G + t;
  float ls = 0.f;
#pragma unroll
  for (int k = 0; k < KD; ++k) {
    float q = ew[k];
    float d = __fsub_rn(q, x[k]);
    ls = fmaf(d, d, ls);
    op[k * TP] = __fadd_rn(x[k], d);
  }

  // deterministic segmented block reduce (block may straddle one n boundary)
  __shared__ float r0s[BLK], r1s[BLK];
  const int n_lo = (blockIdx.x * BLK) / TP;
  r0s[threadIdx.x] = (n == n_lo) ? ls : 0.f;
  r1s[threadIdx.x] = (n == n_lo) ? 0.f : ls;
  __syncthreads();
  for (int s = BLK / 2; s > 0; s >>= 1) {
    if (threadIdx.x < s) {
      r0s[threadIdx.x] += r0s[threadIdx.x + s];
      r1s[threadIdx.x] += r1s[threadIdx.x + s];
    }
    __syncthreads();
  }
  if (threadIdx.x == 0) {
    partials[((size_t)g * NBLK + blockIdx.x) * 2 + 0] = r0s[0];
    partials[((size_t)g * NBLK + blockIdx.x) * 2 + 1] = r1s[0];
  }
}

// ---- final: fixed-order reduction of per-block partials -> vq_loss[n] (fp32)
__global__ void loss_kernel(const float* __restrict__ partials,
                            float* __restrict__ vq) {
  int n = threadIdx.x;
  if (n >= NB) return;
  float acc = 0.f;
  for (int g = 0; g < NG; ++g) {
    float s = 0.f;
    int b0 = (n * TP) / BLK;
    int b1 = ((n + 1) * TP - 1) / BLK;
    for (int b = b0; b <= b1; ++b) {
      int n_lo = (b * BLK) / TP;
      s += partials[((size_t)g * NBLK + b) * 2 + ((n == n_lo) ? 0 : 1)];
    }
    acc += 0.25f * (s / 80000.0f);  // VQ_COMMIT * mean over (Tp,K)
  }
  vq[n] = acc / 6.0f;  // sum over groups / NUM_GROUPS
}

extern "C" void kernel_launch(void* const* d_in, const int* in_sizes, int n_in,
                              void* d_out, int out_size, void* d_ws, size_t ws_size,
                              hipStream_t stream) {
  const float* z = (const float*)d_in[0];
  const float* emb = (const float*)d_in[1];
  float* out = (float*)d_out;

  float* et = (float*)d_ws;                 // 6*1024*40 floats = 983 KB
  float* e2 = et + (size_t)NG * CB * KD;    // 6144 floats
  float* partials = e2 + (size_t)NG * CB;   // 6*250*2 = 3000 floats

  prep_kernel<<<dim3(CB / 256, NG), 256, 0, stream>>>(emb, et, e2);
  vq_kernel<<<dim3(NBLK, NG), BLK, 0, stream>>>(z, et, e2, out, partials);
  loss_kernel<<<1, 64, 0, stream>>>(partials, out + (size_t)NB * 60 * 8000);
}

// Round 7
// 811.386 us; speedup vs baseline: 1.0028x; 1.0028x over previous
//
#include <hip/hip_runtime.h>
#include <math.h>

#define NG 6
#define KD 40
#define CB 1024
#define NB 32
#define TP 2000
#define ROWS (NB * TP)      // 64000 rows per group
#define BLK 256
#define NBLK (ROWS / BLK)   // 250 blocks per group
#define ZN 480000           // z floats per batch element
#define ZG 80000            // z floats per group
#define CHUNK 128           // codes staged in LDS per iteration

// ---- prep: transpose embeddings (g,k,c) -> et[g][c][k] contiguous, plus fast ||e||^2
__global__ void prep_kernel(const float* __restrict__ emb,
                            float* __restrict__ et, float* __restrict__ e2) {
  int c = blockIdx.x * blockDim.x + threadIdx.x;
  int g = blockIdx.y;
  if (c >= CB) return;
  const float* eg = emb + (size_t)g * KD * CB;
  float* o = et + ((size_t)g * CB + c) * KD;
  float s = 0.f;
#pragma unroll
  for (int k = 0; k < KD; ++k) {
    float v = eg[k * CB + c];
    o[k] = v;
    s = fmaf(v, v, s);
  }
  e2[g * CB + c] = s;
}

// numpy-fp32-exact distance, taking xn = -x (exact sign symmetry:
// fl(xn*e) = -fl(x*e), fsub(dot, m) = fadd(dot, -m) -> bit-identical to r6).
__device__ __forceinline__ float np_dist_neg(const float* __restrict__ xn,
                                             const float* __restrict__ ec,
                                             float x2np) {
  float dot = 0.f, ee = 0.f;
#pragma unroll
  for (int k = 0; k < KD; ++k) {
    float ev = ec[k];
    dot = __fsub_rn(dot, __fmul_rn(xn[k], ev));  // serial ascending, unfused
    ee = __fadd_rn(ee, __fmul_rn(ev, ev));
  }
  return __fadd_rn(__fsub_rn(x2np, __fadd_rn(dot, dot)), ee);
}

// ---- main: one thread per (g, n, t) row; codebook chunks staged in LDS
__global__ __launch_bounds__(BLK) void vq_kernel(
    const float* __restrict__ z, const float* __restrict__ et,
    const float* __restrict__ e2, float* __restrict__ out,
    float* __restrict__ partials) {
  const int g = blockIdx.y;
  const int rid = blockIdx.x * BLK + threadIdx.x;  // 0..63999
  const int n = rid / TP;
  const int t = rid - n * TP;

  const float* zp = z + (size_t)n * ZN + (size_t)g * ZG + t;
  float xn[KD];  // negated row
#pragma unroll
  for (int k = 0; k < KD; ++k) xn[k] = -zp[k * TP];

  const float* etg = et + (size_t)g * CB * KD;
  const float* e2g = e2 + g * CB;

  __shared__ float se[CHUNK * KD];  // 20480 B: chunk of codes, [c][k]
  __shared__ float sh[CHUNK];       // 0.5*||e||^2 seeds

  // pass 1: score = 0.5*e2 - dot  (== (dist - x2)/2 up to fp noise; ranking only)
  float d1 = INFINITY, d2 = INFINITY, d3 = INFINITY;
  int i1 = 0, i2 = 0, i3 = 0;

  for (int ch = 0; ch < CB; ch += CHUNK) {
    __syncthreads();  // protect previous chunk's readers
    const float4* src = (const float4*)(etg + (size_t)ch * KD);
    float4* dst = (float4*)se;
#pragma unroll
    for (int j = 0; j < (CHUNK * KD / 4) / BLK; ++j)
      dst[j * BLK + threadIdx.x] = src[j * BLK + threadIdx.x];
    if (threadIdx.x < CHUNK)
      sh[threadIdx.x] = 0.5f * e2g[ch + threadIdx.x];
    __syncthreads();

    for (int cl = 0; cl < CHUNK; cl += 2) {
      const float* e0 = se + cl * KD;
      const float* e1 = e0 + KD;
      float a0 = sh[cl], a1 = 0.f, a2 = 0.f, a3 = 0.f;
      float b0 = sh[cl + 1], b1 = 0.f, b2 = 0.f, b3 = 0.f;
#pragma unroll
      for (int k = 0; k < KD; k += 4) {
        a0 = fmaf(xn[k + 0], e0[k + 0], a0);
        a1 = fmaf(xn[k + 1], e0[k + 1], a1);
        a2 = fmaf(xn[k + 2], e0[k + 2], a2);
        a3 = fmaf(xn[k + 3], e0[k + 3], a3);
        b0 = fmaf(xn[k + 0], e1[k + 0], b0);
        b1 = fmaf(xn[k + 1], e1[k + 1], b1);
        b2 = fmaf(xn[k + 2], e1[k + 2], b2);
        b3 = fmaf(xn[k + 3], e1[k + 3], b3);
      }
      float sa = (a0 + a1) + (a2 + a3);
      float sb = (b0 + b1) + (b2 + b3);
      int c0 = ch + cl, c1 = c0 + 1;
      {
        bool u1 = sa < d1, u2 = sa < d2, u3 = sa < d3;
        d3 = u2 ? d2 : (u3 ? sa : d3); i3 = u2 ? i2 : (u3 ? c0 : i3);
        d2 = u1 ? d1 : (u2 ? sa : d2); i2 = u1 ? i1 : (u2 ? c0 : i2);
        d1 = u1 ? sa : d1;             i1 = u1 ? c0 : i1;
      }
      {
        bool u1 = sb < d1, u2 = sb < d2, u3 = sb < d3;
        d3 = u2 ? d2 : (u3 ? sb : d3); i3 = u2 ? i2 : (u3 ? c1 : i3);
        d2 = u1 ? d1 : (u2 ? sb : d2); i2 = u1 ? i1 : (u2 ? c1 : i2);
        d1 = u1 ? sb : d1;             i1 = u1 ? c1 : i1;
      }
    }
  }

  // pass 2: numpy-fp32-exact re-score of top-3 (identical decision path to r6).
  // x2np: 8 pairwise accumulators over pre-rounded squares (xn*xn == x*x exact).
  float r[8];
#pragma unroll
  for (int j = 0; j < 8; ++j) r[j] = __fmul_rn(xn[j], xn[j]);
#pragma unroll
  for (int i = 8; i < KD; i += 8)
#pragma unroll
    for (int j = 0; j < 8; ++j)
      r[j] = __fadd_rn(r[j], __fmul_rn(xn[i + j], xn[i + j]));
  float x2np = __fadd_rn(__fadd_rn(__fadd_rn(r[0], r[1]), __fadd_rn(r[2], r[3])),
                         __fadd_rn(__fadd_rn(r[4], r[5]), __fadd_rn(r[6], r[7])));

  int ca = i1, cb = i2, cc = i3, tmp;
  if (ca > cb) { tmp = ca; ca = cb; cb = tmp; }
  if (cb > cc) { tmp = cb; cb = cc; cc = tmp; }
  if (ca > cb) { tmp = ca; ca = cb; cb = tmp; }

  float da = np_dist_neg(xn, etg + ca * KD, x2np);
  float db = np_dist_neg(xn, etg + cb * KD, x2np);
  float dc = np_dist_neg(xn, etg + cc * KD, x2np);
  int bi = ca;
  float bd = da;
  if (db < bd) { bi = cb; bd = db; }
  if (dc < bd) { bi = cc; bd = dc; }

  // outputs: STE value fl(x + fl(q - x)); commitment partial (q-x)^2
  const float* ew = etg + bi * KD;
  float* op = out + (size_t)n * ZN + (size_t)g * ZG + t;
  float ls = 0.f;
#pragma unroll
  for (int k = 0; k < KD; ++k) {
    float q = ew[k];
    float d = __fadd_rn(q, xn[k]);       // q - x
    ls = fmaf(d, d, ls);
    op[k * TP] = __fsub_rn(d, xn[k]);    // x + d
  }

  // deterministic segmented block reduce (block may straddle one n boundary)
  __shared__ float r0s[BLK], r1s[BLK];
  const int n_lo = (blockIdx.x * BLK) / TP;
  r0s[threadIdx.x] = (n == n_lo) ? ls : 0.f;
  r1s[threadIdx.x] = (n == n_lo) ? 0.f : ls;
  __syncthreads();
  for (int s = BLK / 2; s > 0; s >>= 1) {
    if (threadIdx.x < s) {
      r0s[threadIdx.x] += r0s[threadIdx.x + s];
      r1s[threadIdx.x] += r1s[threadIdx.x + s];
    }
    __syncthreads();
  }
  if (threadIdx.x == 0) {
    partials[((size_t)g * NBLK + blockIdx.x) * 2 + 0] = r0s[0];
    partials[((size_t)g * NBLK + blockIdx.x) * 2 + 1] = r1s[0];
  }
}

// ---- final: fixed-order reduction of per-block partials -> vq_loss[n] (fp32)
__global__ void loss_kernel(const float* __restrict__ partials,
                            float* __restrict__ vq) {
  int n = threadIdx.x;
  if (n >= NB) return;
  float acc = 0.f;
  for (int g = 0; g < NG; ++g) {
    float s = 0.f;
    int b0 = (n * TP) / BLK;
    int b1 = ((n + 1) * TP - 1) / BLK;
    for (int b = b0; b <= b1; ++b) {
      int n_lo = (b * BLK) / TP;
      s += partials[((size_t)g * NBLK + b) * 2 + ((n == n_lo) ? 0 : 1)];
    }
    acc += 0.25f * (s / 80000.0f);  // VQ_COMMIT * mean over (Tp,K)
  }
  vq[n] = acc / 6.0f;  // sum over groups / NUM_GROUPS
}

extern "C" void kernel_launch(void* const* d_in, const int* in_sizes, int n_in,
                              void* d_out, int out_size, void* d_ws, size_t ws_size,
                              hipStream_t stream) {
  const float* z = (const float*)d_in[0];
  const float* emb = (const float*)d_in[1];
  float* out = (float*)d_out;

  float* et = (float*)d_ws;                 // 6*1024*40 floats
  float* e2 = et + (size_t)NG * CB * KD;    // 6144 floats
  float* partials = e2 + (size_t)NG * CB;   // 6*250*2 floats

  prep_kernel<<<dim3(CB / 256, NG), 256, 0, stream>>>(emb, et, e2);
  vq_kernel<<<dim3(NBLK, NG), BLK, 0, stream>>>(z, et, e2, out, partials);
  loss_kernel<<<1, 64, 0, stream>>>(partials, out + (size_t)NB * 60 * 8000);
}

// Round 8
// 609.194 us; speedup vs baseline: 1.3356x; 1.3319x over previous
//
#include <hip/hip_runtime.h>
#include <math.h>

#define NG 6
#define KD 40
#define CB 1024
#define NB 32
#define TP 2000
#define RPB 256              // rows per block (4 waves x 64)
#define NBLK 250             // 64000 / 256
#define ZN 480000
#define ZG 80000
#define ECH 64               // codes per LDS chunk
#define NCH (CB / ECH)       // 16
#define EST 52               // LDS row stride (bf16 elems) for X/E

typedef __attribute__((ext_vector_type(8))) short bf16x8;
typedef __attribute__((ext_vector_type(16))) float f32x16;

// ---- prep: transpose embeddings (g,k,c) -> et[g][c][k] contiguous, plus ||e||^2
__global__ void prep_kernel(const float* __restrict__ emb,
                            float* __restrict__ et, float* __restrict__ e2) {
  int c = blockIdx.x * blockDim.x + threadIdx.x;
  int g = blockIdx.y;
  if (c >= CB) return;
  const float* eg = emb + (size_t)g * KD * CB;
  float* o = et + ((size_t)g * CB + c) * KD;
  float s = 0.f;
#pragma unroll
  for (int k = 0; k < KD; ++k) {
    float v = eg[k * CB + c];
    o[k] = v;
    s = fmaf(v, v, s);
  }
  e2[g * CB + c] = s;
}

__device__ __forceinline__ unsigned short bf16rne(float v) {
  unsigned u = __float_as_uint(v);
  return (unsigned short)((u + 0x7FFFu + ((u >> 16) & 1u)) >> 16);
}
__device__ __forceinline__ float bf16val(unsigned short h) {
  return __uint_as_float(((unsigned)h) << 16);
}
__device__ __forceinline__ void bf16split(float v, unsigned short& h, unsigned short& l) {
  h = bf16rne(v);
  float lo = v - bf16val(h);   // exact
  l = bf16rne(lo);
}

__device__ __forceinline__ bf16x8 ldfrag(const unsigned short* p) {
  union { unsigned long long q[2]; bf16x8 v; } u;
  u.q[0] = *(const unsigned long long*)(p);
  u.q[1] = *(const unsigned long long*)(p + 4);
  return u.v;
}

// numpy-fp32-exact distance (verified in r6): serial ascending-k unfused
__device__ __forceinline__ float np_dist(const float* __restrict__ x,
                                         const float* __restrict__ ec,
                                         float x2np) {
  float dot = 0.f, ee = 0.f;
#pragma unroll
  for (int k = 0; k < KD; ++k) {
    float ev = ec[k];
    dot = __fadd_rn(dot, __fmul_rn(x[k], ev));
    ee = __fadd_rn(ee, __fmul_rn(ev, ev));
  }
  return __fadd_rn(__fsub_rn(x2np, __fadd_rn(dot, dot)), ee);
}

#define INS(TD, TI, GM, GB) { \
  bool u1 = (GM) < TD[0]; bool u2 = (GM) < TD[1]; bool u3 = (GM) < TD[2]; \
  TD[2] = u2 ? TD[1] : (u3 ? (GM) : TD[2]); TI[2] = u2 ? TI[1] : (u3 ? (GB) : TI[2]); \
  TD[1] = u1 ? TD[0] : (u2 ? (GM) : TD[1]); TI[1] = u1 ? TI[0] : (u2 ? (GB) : TI[1]); \
  TD[0] = u1 ? (GM) : TD[0]; TI[0] = u1 ? (GB) : TI[0]; }

__global__ __launch_bounds__(RPB) void vq_kernel(
    const float* __restrict__ z, const float* __restrict__ et,
    const float* __restrict__ e2, float* __restrict__ out,
    float* __restrict__ partials) {
  const int g = blockIdx.y;
  const int bb = blockIdx.x;
  const int tid = threadIdx.x;
  const int lane = tid & 63;
  const int gg = lane >> 5;        // k-group within wave
  const int j32 = lane & 31;
  const int wb = (tid >> 6) * 64;  // wave's row base within block

  const float* etg = et + (size_t)g * CB * KD;
  const float* e2g = e2 + g * CB;

  __shared__ unsigned short XhS[RPB][EST], XlS[RPB][EST];
  __shared__ unsigned short EhS[ECH][EST], ElS[ECH][EST];
  __shared__ float r0s[RPB], r1s[RPB];

  // ---- stage X (negated, bf16 hi/lo) : thread tid owns row tid
  {
    int rid = bb * RPB + tid;
    int n = rid / TP;
    int tt = rid - n * TP;
    const float* zp = z + (size_t)n * ZN + (size_t)g * ZG + tt;
    float xv[KD];
#pragma unroll
    for (int k = 0; k < KD; ++k) xv[k] = -zp[(size_t)k * TP];
#pragma unroll
    for (int p = 0; p < KD / 2; ++p) {
      unsigned short h0, l0, h1, l1;
      bf16split(xv[2 * p], h0, l0);
      bf16split(xv[2 * p + 1], h1, l1);
      *(unsigned int*)&XhS[tid][2 * p] = (unsigned)h0 | ((unsigned)h1 << 16);
      *(unsigned int*)&XlS[tid][2 * p] = (unsigned)l0 | ((unsigned)l1 << 16);
    }
    // k-slots 40..47: ones against the e2 splits (hi only)
    *(unsigned int*)&XhS[tid][40] = 0x3F803F80u;
    *(unsigned int*)&XhS[tid][42] = 0x00003F80u;
    *(unsigned int*)&XhS[tid][44] = 0u;
    *(unsigned int*)&XhS[tid][46] = 0u;
    *(unsigned int*)&XlS[tid][40] = 0u;
    *(unsigned int*)&XlS[tid][42] = 0u;
    *(unsigned int*)&XlS[tid][44] = 0u;
    *(unsigned int*)&XlS[tid][46] = 0u;
  }

  // ---- E-chunk prefetch registers
  const int ec = tid >> 2;          // code within chunk
  const int ekb = (tid & 3) * 10;   // k-base this thread stages
  float pf[10];
  float e2pf = 0.f;
  {
    const float* ep = etg + (size_t)ec * KD + ekb;
#pragma unroll
    for (int i = 0; i < 10; ++i) pf[i] = ep[i];
    if ((tid & 3) == 0) e2pf = 0.5f * e2g[ec];
  }

  f32x16 zacc;
#pragma unroll
  for (int i = 0; i < 16; ++i) zacc[i] = 0.f;

  bf16x8 BH0[3], BL0[3], BH1[3], BL1[3];
  float td0[3] = {INFINITY, INFINITY, INFINITY};
  float td1[3] = {INFINITY, INFINITY, INFINITY};
  int ti0[3] = {0, 0, 0}, ti1[3] = {0, 0, 0};

  for (int ch = 0; ch < NCH; ++ch) {
    // write prefetched E chunk (hi/lo split) into LDS
    {
      unsigned short hs[10], lss[10];
#pragma unroll
      for (int i = 0; i < 10; ++i) bf16split(pf[i], hs[i], lss[i]);
#pragma unroll
      for (int p = 0; p < 5; ++p) {
        *(unsigned int*)&EhS[ec][ekb + 2 * p] = (unsigned)hs[2 * p] | ((unsigned)hs[2 * p + 1] << 16);
        *(unsigned int*)&ElS[ec][ekb + 2 * p] = (unsigned)lss[2 * p] | ((unsigned)lss[2 * p + 1] << 16);
      }
      if ((tid & 3) == 0) {
        unsigned short p0 = bf16rne(e2pf);
        float v1 = e2pf - bf16val(p0);
        unsigned short p1 = bf16rne(v1);
        float v2 = v1 - bf16val(p1);
        unsigned short p2 = bf16rne(v2);
        *(unsigned int*)&EhS[ec][40] = (unsigned)p0 | ((unsigned)p1 << 16);
        *(unsigned int*)&EhS[ec][42] = (unsigned)p2;
        *(unsigned int*)&EhS[ec][44] = 0u;
        *(unsigned int*)&EhS[ec][46] = 0u;
        *(unsigned int*)&ElS[ec][40] = 0u;
        *(unsigned int*)&ElS[ec][42] = 0u;
        *(unsigned int*)&ElS[ec][44] = 0u;
        *(unsigned int*)&ElS[ec][46] = 0u;
      }
    }
    __syncthreads();

    // prefetch next chunk while computing this one (T14)
    if (ch + 1 < NCH) {
      const float* ep = etg + (size_t)((ch + 1) * ECH + ec) * KD + ekb;
#pragma unroll
      for (int i = 0; i < 10; ++i) pf[i] = ep[i];
      if ((tid & 3) == 0) e2pf = 0.5f * e2g[(ch + 1) * ECH + ec];
    }

    if (ch == 0) {
      // load B fragments (rows fixed per wave) once, after X is staged
      int r0 = wb + j32, r1 = r0 + 32;
#pragma unroll
      for (int s = 0; s < 3; ++s) {
        int kb = s * 16 + gg * 8;
        BH0[s] = ldfrag(&XhS[r0][kb]);
        BL0[s] = ldfrag(&XlS[r0][kb]);
        BH1[s] = ldfrag(&XhS[r1][kb]);
        BL1[s] = ldfrag(&XlS[r1][kb]);
      }
    }

#pragma unroll
    for (int lt = 0; lt < 2; ++lt) {
      const int m = lt * 32 + j32;
      const int ct32 = (ch * 2 + lt) * 32;
      f32x16 a0, a1;
      {
        bf16x8 eh = ldfrag(&EhS[m][0 + gg * 8]);
        bf16x8 el = ldfrag(&ElS[m][0 + gg * 8]);
        a0 = __builtin_amdgcn_mfma_f32_32x32x16_bf16(eh, BH0[0], zacc, 0, 0, 0);
        a1 = __builtin_amdgcn_mfma_f32_32x32x16_bf16(eh, BH1[0], zacc, 0, 0, 0);
        a0 = __builtin_amdgcn_mfma_f32_32x32x16_bf16(eh, BL0[0], a0, 0, 0, 0);
        a1 = __builtin_amdgcn_mfma_f32_32x32x16_bf16(eh, BL1[0], a1, 0, 0, 0);
        a0 = __builtin_amdgcn_mfma_f32_32x32x16_bf16(el, BH0[0], a0, 0, 0, 0);
        a1 = __builtin_amdgcn_mfma_f32_32x32x16_bf16(el, BH1[0], a1, 0, 0, 0);
      }
#pragma unroll
      for (int s = 1; s < 3; ++s) {
        bf16x8 eh = ldfrag(&EhS[m][s * 16 + gg * 8]);
        bf16x8 el = ldfrag(&ElS[m][s * 16 + gg * 8]);
        a0 = __builtin_amdgcn_mfma_f32_32x32x16_bf16(eh, BH0[s], a0, 0, 0, 0);
        a1 = __builtin_amdgcn_mfma_f32_32x32x16_bf16(eh, BH1[s], a1, 0, 0, 0);
        a0 = __builtin_amdgcn_mfma_f32_32x32x16_bf16(eh, BL0[s], a0, 0, 0, 0);
        a1 = __builtin_amdgcn_mfma_f32_32x32x16_bf16(eh, BL1[s], a1, 0, 0, 0);
        a0 = __builtin_amdgcn_mfma_f32_32x32x16_bf16(el, BH0[s], a0, 0, 0, 0);
        a1 = __builtin_amdgcn_mfma_f32_32x32x16_bf16(el, BH1[s], a1, 0, 0, 0);
      }
      // group-min tracking: acc reg r holds code ct32 + (r&3) + 8*(r>>2) + 4*gg
#pragma unroll
      for (int q = 0; q < 4; ++q) {
        int gb = ct32 + 8 * q + 4 * gg;
        float gm0 = fminf(fminf(a0[4 * q], a0[4 * q + 1]), fminf(a0[4 * q + 2], a0[4 * q + 3]));
        INS(td0, ti0, gm0, gb);
        float gm1 = fminf(fminf(a1[4 * q], a1[4 * q + 1]), fminf(a1[4 * q + 2], a1[4 * q + 3]));
        INS(td1, ti1, gm1, gb);
      }
    }
    __syncthreads();
  }

  // ---- pass 2: np-fp32-exact re-score of candidates; epilogue STE + loss
  const int n_lo = (bb * RPB) / TP;
  float lsA = 0.f, lsB = 0.f;

#pragma unroll
  for (int set = 0; set < 2; ++set) {
    int rowloc = wb + j32 + set * 32;
    int rid = bb * RPB + rowloc;
    int n = rid / TP;
    int tt = rid - n * TP;
    const float* zp = z + (size_t)n * ZN + (size_t)g * ZG + tt;
    float x[KD];
#pragma unroll
    for (int k = 0; k < KD; ++k) x[k] = zp[(size_t)k * TP];

    // x2np: numpy pairwise (8 accumulators over pre-rounded squares) — verified r6
    float r[8];
#pragma unroll
    for (int q = 0; q < 8; ++q) r[q] = __fmul_rn(x[q], x[q]);
#pragma unroll
    for (int i = 8; i < KD; i += 8)
#pragma unroll
      for (int q = 0; q < 8; ++q)
        r[q] = __fadd_rn(r[q], __fmul_rn(x[i + q], x[i + q]));
    float x2np = __fadd_rn(__fadd_rn(__fadd_rn(r[0], r[1]), __fadd_rn(r[2], r[3])),
                           __fadd_rn(__fadd_rn(r[4], r[5]), __fadd_rn(r[6], r[7])));

    int ga = set ? ti1[0] : ti0[0];
    int gbv = set ? ti1[1] : ti0[1];
    int gc = set ? ti1[2] : ti0[2];
    int tswp;
    if (ga > gbv) { tswp = ga; ga = gbv; gbv = tswp; }
    if (gbv > gc) { tswp = gbv; gbv = gc; gc = tswp; }
    if (ga > gbv) { tswp = ga; ga = gbv; gbv = tswp; }

    float bd = INFINITY;
    int bi = CB;
    int gl[3] = {ga, gbv, gc};
#pragma unroll
    for (int gi = 0; gi < 3; ++gi) {
#pragma unroll
      for (int jj = 0; jj < 4; ++jj) {
        int c = gl[gi] + jj;
        float d = np_dist(x, etg + (size_t)c * KD, x2np);
        if (d < bd) { bd = d; bi = c; }
      }
    }
    // merge with partner lane (other code-half of the same row)
    float od = __shfl_xor(bd, 32);
    int oi = __shfl_xor(bi, 32);
    if (od < bd || (od == bd && oi < bi)) { bd = od; bi = oi; }

    // epilogue: this lane writes its k-half
    const float* eb = etg + (size_t)bi * KD;
    float* op = out + (size_t)n * ZN + (size_t)g * ZG + tt;
    float ls = 0.f;
#pragma unroll
    for (int kk = 0; kk < 20; ++kk) {
      int k = gg * 20 + kk;
      float qv = eb[k];
      float d = __fsub_rn(qv, x[k]);
      ls = fmaf(d, d, ls);
      op[(size_t)k * TP] = __fadd_rn(x[k], d);
    }
    if (n == n_lo) lsA += ls; else lsB += ls;
  }

  // ---- deterministic segmented block reduce
  r0s[tid] = lsA;
  r1s[tid] = lsB;
  __syncthreads();
  for (int s = RPB / 2; s > 0; s >>= 1) {
    if (tid < s) {
      r0s[tid] += r0s[tid + s];
      r1s[tid] += r1s[tid + s];
    }
    __syncthreads();
  }
  if (tid == 0) {
    partials[((size_t)g * NBLK + bb) * 2 + 0] = r0s[0];
    partials[((size_t)g * NBLK + bb) * 2 + 1] = r1s[0];
  }
}

// ---- final: fixed-order reduction of per-block partials -> vq_loss[n]
__global__ void loss_kernel(const float* __restrict__ partials,
                            float* __restrict__ vq) {
  int n = threadIdx.x;
  if (n >= NB) return;
  float acc = 0.f;
  for (int g = 0; g < NG; ++g) {
    float s = 0.f;
    int b0 = (n * TP) / RPB;
    int b1 = ((n + 1) * TP - 1) / RPB;
    for (int b = b0; b <= b1; ++b) {
      int n_lo = (b * RPB) / TP;
      s += partials[((size_t)g * NBLK + b) * 2 + ((n == n_lo) ? 0 : 1)];
    }
    acc += 0.25f * (s / 80000.0f);
  }
  vq[n] = acc / 6.0f;
}

extern "C" void kernel_launch(void* const* d_in, const int* in_sizes, int n_in,
                              void* d_out, int out_size, void* d_ws, size_t ws_size,
                              hipStream_t stream) {
  const float* z = (const float*)d_in[0];
  const float* emb = (const float*)d_in[1];
  float* out = (float*)d_out;

  float* et = (float*)d_ws;
  float* e2 = et + (size_t)NG * CB * KD;
  float* partials = e2 + (size_t)NG * CB;

  prep_kernel<<<dim3(CB / 256, NG), 256, 0, stream>>>(emb, et, e2);
  vq_kernel<<<dim3(NBLK, NG), RPB, 0, stream>>>(z, et, e2, out, partials);
  loss_kernel<<<1, 64, 0, stream>>>(partials, out + (size_t)NB * 60 * 8000);
}

// Round 9
// 357.167 us; speedup vs baseline: 2.2780x; 1.7056x over previous
//
#include <hip/hip_runtime.h>
#include <math.h>

#define NG 6
#define KD 40
#define CB 1024
#define NB 32
#define TP 2000
#define RPB 128              // rows per block (4 waves x 32)
#define THREADS 256
#define NBLK 500             // 64000 / 128
#define ZN 480000
#define ZG 80000
#define ECH 64               // codes per LDS chunk
#define NCH (CB / ECH)       // 16
#define EST 52               // bf16 LDS row stride (shorts)
#define FST 44               // fp32 LDS row stride (floats)
#define EPS_D 0.02f

typedef __attribute__((ext_vector_type(8))) short bf16x8;
typedef __attribute__((ext_vector_type(16))) float f32x16;

// ---- prep: transpose embeddings -> et[g][c][k]; np-exact ||e||^2 (serial unfused)
__global__ void prep_kernel(const float* __restrict__ emb,
                            float* __restrict__ et, float* __restrict__ e2) {
  int c = blockIdx.x * blockDim.x + threadIdx.x;
  int g = blockIdx.y;
  if (c >= CB) return;
  const float* eg = emb + (size_t)g * KD * CB;
  float* o = et + ((size_t)g * CB + c) * KD;
  float s = 0.f;
#pragma unroll
  for (int k = 0; k < KD; ++k) {
    float v = eg[k * CB + c];
    o[k] = v;
    s = __fadd_rn(s, __fmul_rn(v, v));   // np semantics
  }
  e2[g * CB + c] = s;
}

__device__ __forceinline__ unsigned short bf16rne(float v) {
  unsigned u = __float_as_uint(v);
  return (unsigned short)((u + 0x7FFFu + ((u >> 16) & 1u)) >> 16);
}
__device__ __forceinline__ float bf16val(unsigned short h) {
  return __uint_as_float(((unsigned)h) << 16);
}
__device__ __forceinline__ void bf16split(float v, unsigned short& h, unsigned short& l) {
  h = bf16rne(v);
  float lo = v - bf16val(h);   // exact (Sterbenz)
  l = bf16rne(lo);
}
__device__ __forceinline__ bf16x8 ldfrag(const unsigned short* p) {
  union { unsigned long long q[2]; bf16x8 v; } u;
  u.q[0] = *(const unsigned long long*)(p);
  u.q[1] = *(const unsigned long long*)(p + 4);
  return u.v;
}

__global__ __launch_bounds__(THREADS, 3) void vq_kernel(
    const float* __restrict__ z, const float* __restrict__ et,
    const float* __restrict__ e2, float* __restrict__ out,
    float* __restrict__ partials) {
  const int g = blockIdx.y;
  const int bb = blockIdx.x;
  const int tid = threadIdx.x;
  const int lane = tid & 63;
  const int gg = lane >> 5;
  const int j32 = lane & 31;
  const int rowloc = (tid >> 6) * 32 + j32;
  const int rid = bb * RPB + rowloc;
  const int n = rid / TP;
  const int tt = rid - n * TP;

  const float* etg = et + (size_t)g * CB * KD;
  const float* e2g = e2 + g * CB;

  __shared__ unsigned short EhS[ECH][EST], ElS[ECH][EST];
  __shared__ float EF[ECH][FST];
  __shared__ float E2S[ECH];
  __shared__ float r0s[THREADS], r1s[THREADS];

  // ---- row x in registers (coalesced loads), x2np (numpy pairwise-8, verified r6)
  const float* zp = z + (size_t)n * ZN + (size_t)g * ZG + tt;
  float x[KD];
#pragma unroll
  for (int k = 0; k < KD; ++k) x[k] = zp[(size_t)k * TP];
  float x2np;
  {
    float r[8];
#pragma unroll
    for (int j = 0; j < 8; ++j) r[j] = __fmul_rn(x[j], x[j]);
#pragma unroll
    for (int i = 8; i < KD; i += 8)
#pragma unroll
      for (int j = 0; j < 8; ++j)
        r[j] = __fadd_rn(r[j], __fmul_rn(x[i + j], x[i + j]));
    x2np = __fadd_rn(__fadd_rn(__fadd_rn(r[0], r[1]), __fadd_rn(r[2], r[3])),
                     __fadd_rn(__fadd_rn(r[4], r[5]), __fadd_rn(r[6], r[7])));
  }

  // ---- B fragments from -x, static indices per gg half (no dynamic x[] indexing)
  bf16x8 xh[3], xl[3];
#define PACK8(DH, DL, B0) { \
    union { unsigned short s[8]; bf16x8 v; } uh, ul; \
    _Pragma("unroll") \
    for (int j = 0; j < 8; ++j) { \
      unsigned short h, l; bf16split(-x[(B0) + j], h, l); \
      uh.s[j] = h; ul.s[j] = l; } \
    DH = uh.v; DL = ul.v; }
  if (gg == 0) {
    PACK8(xh[0], xl[0], 0)
    PACK8(xh[1], xl[1], 16)
    PACK8(xh[2], xl[2], 32)
  } else {
    PACK8(xh[0], xl[0], 8)
    PACK8(xh[1], xl[1], 24)
    union { unsigned short s[8]; bf16x8 v; } uh;
#pragma unroll
    for (int j = 0; j < 8; ++j) uh.s[j] = (j < 3) ? (unsigned short)0x3F80 : (unsigned short)0;
    xh[2] = uh.v;
    union { unsigned short s[8]; bf16x8 v; } uz;
#pragma unroll
    for (int j = 0; j < 8; ++j) uz.s[j] = 0;
    xl[2] = uz.v;
  }

  f32x16 zacc;
#pragma unroll
  for (int i = 0; i < 16; ++i) zacc[i] = 0.f;

  // ---- E-chunk prefetch (thread stages 10 floats of one code)
  const int ec = tid >> 2;
  const int ekb = (tid & 3) * 10;
  float pf[10];
  float e2v = 0.f;
  {
    const float* ep = etg + (size_t)ec * KD + ekb;
#pragma unroll
    for (int i = 0; i < 10; ++i) pf[i] = ep[i];
    if ((tid & 3) == 0) e2v = e2g[ec];
  }

  float best_d = INFINITY;
  int best_i = CB;

  for (int ch = 0; ch < NCH; ++ch) {
    __syncthreads();  // previous chunk's readers done
    // stage: fp32 copy + bf16 hi/lo split + seeds
    {
      unsigned short hs[10], lss[10];
#pragma unroll
      for (int i = 0; i < 10; ++i) {
        EF[ec][ekb + i] = pf[i];
        bf16split(pf[i], hs[i], lss[i]);
      }
#pragma unroll
      for (int p = 0; p < 5; ++p) {
        *(unsigned int*)&EhS[ec][ekb + 2 * p] = (unsigned)hs[2 * p] | ((unsigned)hs[2 * p + 1] << 16);
        *(unsigned int*)&ElS[ec][ekb + 2 * p] = (unsigned)lss[2 * p] | ((unsigned)lss[2 * p + 1] << 16);
      }
      if ((tid & 3) == 0) {
        float sv = 0.5f * e2v;
        unsigned short p0 = bf16rne(sv);
        float v1 = sv - bf16val(p0);
        unsigned short p1 = bf16rne(v1);
        unsigned short p2 = bf16rne(v1 - bf16val(p1));
        *(unsigned int*)&EhS[ec][40] = (unsigned)p0 | ((unsigned)p1 << 16);
        *(unsigned int*)&EhS[ec][42] = (unsigned)p2;
        *(unsigned int*)&EhS[ec][44] = 0u;
        *(unsigned int*)&EhS[ec][46] = 0u;
        *(unsigned int*)&ElS[ec][40] = 0u;
        *(unsigned int*)&ElS[ec][42] = 0u;
        *(unsigned int*)&ElS[ec][44] = 0u;
        *(unsigned int*)&ElS[ec][46] = 0u;
        E2S[ec] = e2v;
      }
    }
    __syncthreads();

    // prefetch next chunk (overlaps with MFMA below)
    if (ch + 1 < NCH) {
      const float* ep = etg + (size_t)((ch + 1) * ECH + ec) * KD + ekb;
#pragma unroll
      for (int i = 0; i < 10; ++i) pf[i] = ep[i];
      if ((tid & 3) == 0) e2v = e2g[(ch + 1) * ECH + ec];
    }

#pragma unroll
    for (int lt = 0; lt < 2; ++lt) {
      const int m = lt * 32 + j32;
      f32x16 a;
      {
        bf16x8 eh = ldfrag(&EhS[m][0 + gg * 8]);
        bf16x8 el = ldfrag(&ElS[m][0 + gg * 8]);
        a = __builtin_amdgcn_mfma_f32_32x32x16_bf16(eh, xh[0], zacc, 0, 0, 0);
        a = __builtin_amdgcn_mfma_f32_32x32x16_bf16(eh, xl[0], a, 0, 0, 0);
        a = __builtin_amdgcn_mfma_f32_32x32x16_bf16(el, xh[0], a, 0, 0, 0);
      }
#pragma unroll
      for (int s = 1; s < 3; ++s) {
        bf16x8 eh = ldfrag(&EhS[m][s * 16 + gg * 8]);
        bf16x8 el = ldfrag(&ElS[m][s * 16 + gg * 8]);
        a = __builtin_amdgcn_mfma_f32_32x32x16_bf16(eh, xh[s], a, 0, 0, 0);
        a = __builtin_amdgcn_mfma_f32_32x32x16_bf16(eh, xl[s], a, 0, 0, 0);
        a = __builtin_amdgcn_mfma_f32_32x32x16_bf16(el, xh[s], a, 0, 0, 0);
      }
      // scores: a[r] = 0.5*e2 - x.e for code ch*64 + lt*32 + 8*(r>>2) + 4*gg + (r&3)
#pragma unroll
      for (int q = 0; q < 4; ++q) {
        float gm = fminf(fminf(a[4 * q], a[4 * q + 1]), fminf(a[4 * q + 2], a[4 * q + 3]));
        if (fmaf(2.f, gm, x2np) < best_d + EPS_D) {
#pragma unroll
          for (int j = 0; j < 4; ++j) {
            float sc = a[4 * q + j];
            if (fmaf(2.f, sc, x2np) < best_d + EPS_D) {
              int cl = lt * 32 + 8 * q + 4 * gg + j;
              // np-fp32-exact distance from LDS (serial ascending, unfused)
              float dot = 0.f;
              const float* ef = EF[cl];
#pragma unroll
              for (int k = 0; k < KD; ++k)
                dot = __fadd_rn(dot, __fmul_rn(x[k], ef[k]));
              float d = __fadd_rn(__fsub_rn(x2np, __fadd_rn(dot, dot)), E2S[cl]);
              if (d < best_d) { best_d = d; best_i = ch * ECH + cl; }
            }
          }
        }
      }
    }
  }

  // merge the two k-half lanes of each row (index tiebreak = np first-min)
  {
    float od = __shfl_xor(best_d, 32);
    int oi = __shfl_xor(best_i, 32);
    if (od < best_d || (od == best_d && oi < best_i)) { best_d = od; best_i = oi; }
  }

  // ---- epilogue: STE write + loss partial, static k-halves per gg
  const float4* eb4 = (const float4*)(etg + (size_t)best_i * KD);
  float* op = out + (size_t)n * ZN + (size_t)g * ZG + tt;
  float ls = 0.f;
  if (gg == 0) {
#pragma unroll
    for (int p = 0; p < 5; ++p) {
      float4 v = eb4[p];
      float q0 = v.x, q1 = v.y, q2 = v.z, q3 = v.w;
      int k = 4 * p;
      float d0 = __fsub_rn(q0, x[k + 0]); ls = fmaf(d0, d0, ls); op[(size_t)(k + 0) * TP] = __fadd_rn(x[k + 0], d0);
      float d1 = __fsub_rn(q1, x[k + 1]); ls = fmaf(d1, d1, ls); op[(size_t)(k + 1) * TP] = __fadd_rn(x[k + 1], d1);
      float d2 = __fsub_rn(q2, x[k + 2]); ls = fmaf(d2, d2, ls); op[(size_t)(k + 2) * TP] = __fadd_rn(x[k + 2], d2);
      float d3 = __fsub_rn(q3, x[k + 3]); ls = fmaf(d3, d3, ls); op[(size_t)(k + 3) * TP] = __fadd_rn(x[k + 3], d3);
    }
  } else {
#pragma unroll
    for (int p = 5; p < 10; ++p) {
      float4 v = eb4[p];
      float q0 = v.x, q1 = v.y, q2 = v.z, q3 = v.w;
      int k = 4 * p;
      float d0 = __fsub_rn(q0, x[k + 0]); ls = fmaf(d0, d0, ls); op[(size_t)(k + 0) * TP] = __fadd_rn(x[k + 0], d0);
      float d1 = __fsub_rn(q1, x[k + 1]); ls = fmaf(d1, d1, ls); op[(size_t)(k + 1) * TP] = __fadd_rn(x[k + 1], d1);
      float d2 = __fsub_rn(q2, x[k + 2]); ls = fmaf(d2, d2, ls); op[(size_t)(k + 2) * TP] = __fadd_rn(x[k + 2], d2);
      float d3 = __fsub_rn(q3, x[k + 3]); ls = fmaf(d3, d3, ls); op[(size_t)(k + 3) * TP] = __fadd_rn(x[k + 3], d3);
    }
  }

  // ---- deterministic segmented block reduce (block straddles <=1 n boundary)
  const int n_lo = (bb * RPB) / TP;
  r0s[tid] = (n == n_lo) ? ls : 0.f;
  r1s[tid] = (n == n_lo) ? 0.f : ls;
  __syncthreads();
  for (int s = THREADS / 2; s > 0; s >>= 1) {
    if (tid < s) {
      r0s[tid] += r0s[tid + s];
      r1s[tid] += r1s[tid + s];
    }
    __syncthreads();
  }
  if (tid == 0) {
    partials[((size_t)g * NBLK + bb) * 2 + 0] = r0s[0];
    partials[((size_t)g * NBLK + bb) * 2 + 1] = r1s[0];
  }
}

// ---- final: fixed-order reduction of per-block partials -> vq_loss[n]
__global__ void loss_kernel(const float* __restrict__ partials,
                            float* __restrict__ vq) {
  int n = threadIdx.x;
  if (n >= NB) return;
  float acc = 0.f;
  for (int g = 0; g < NG; ++g) {
    float s = 0.f;
    int b0 = (n * TP) / RPB;
    int b1 = ((n + 1) * TP - 1) / RPB;
    for (int b = b0; b <= b1; ++b) {
      int n_lo = (b * RPB) / TP;
      s += partials[((size_t)g * NBLK + b) * 2 + ((n == n_lo) ? 0 : 1)];
    }
    acc += 0.25f * (s / 80000.0f);
  }
  vq[n] = acc / 6.0f;
}

extern "C" void kernel_launch(void* const* d_in, const int* in_sizes, int n_in,
                              void* d_out, int out_size, void* d_ws, size_t ws_size,
                              hipStream_t stream) {
  const float* z = (const float*)d_in[0];
  const float* emb = (const float*)d_in[1];
  float* out = (float*)d_out;

  float* et = (float*)d_ws;
  float* e2 = et + (size_t)NG * CB * KD;
  float* partials = e2 + (size_t)NG * CB;

  prep_kernel<<<dim3(CB / 256, NG), 256, 0, stream>>>(emb, et, e2);
  vq_kernel<<<dim3(NBLK, NG), THREADS, 0, stream>>>(z, et, e2, out, partials);
  loss_kernel<<<1, 64, 0, stream>>>(partials, out + (size_t)NB * 60 * 8000);
}